// Round 12
// baseline (201.246 us; speedup 1.0000x reference)
//
#include <hip/hip_runtime.h>
#include <stdint.h>

#define DIMS 256
#define NT 4096
#define NROWS 65536
#define THETA 1.5e-4f

typedef float    f32x4_t __attribute__((ext_vector_type(4)));
typedef _Float16 f16x8_t __attribute__((ext_vector_type(8)));
typedef _Float16 f16x4_t __attribute__((ext_vector_type(4)));

// ---- kernel 0: fused se (bit-exact numpy pairwise) + cb16 = fp16(cb*512) ----
__global__ __launch_bounds__(64) void vq_prep(const float* __restrict__ cb,
                                              float* __restrict__ se,
                                              _Float16* __restrict__ cb16){
  __shared__ float sq[256];
  const int k = blockIdx.x;
  const int tid = threadIdx.x;
  float4 v = *(const float4*)(cb + (size_t)k*256 + tid*4);
  f16x4_t p;
  p.x = (_Float16)(v.x * 512.f);
  p.y = (_Float16)(v.y * 512.f);
  p.z = (_Float16)(v.z * 512.f);
  p.w = (_Float16)(v.w * 512.f);
  *(f16x4_t*)(cb16 + (size_t)k*256 + tid*4) = p;
  sq[tid*4+0] = __fmul_rn(v.x, v.x);
  sq[tid*4+1] = __fmul_rn(v.y, v.y);
  sq[tid*4+2] = __fmul_rn(v.z, v.z);
  sq[tid*4+3] = __fmul_rn(v.w, v.w);
  __syncthreads();
  if (tid < 16){
    const int h = tid >> 3, j = tid & 7;
    float r = sq[h*128 + j];
    #pragma unroll
    for (int i = 1; i < 16; ++i) r = __fadd_rn(r, sq[h*128 + j + 8*i]);
    r = __fadd_rn(r, __shfl_xor(r, 1));
    r = __fadd_rn(r, __shfl_xor(r, 2));
    r = __fadd_rn(r, __shfl_xor(r, 4));
    r = __fadd_rn(r, __shfl_xor(r, 8));
    if (tid == 0) se[k] = r;
  }
}

// ================= kernel 1: scores + fused loss + fused output write =================
// 64 rows/block x 1024 codes; 8 waves: wr = row-half (M=2), wc = 64-code stripe.
// Barrier discipline: prefetch loads issued AFTER __syncthreads (never drained by the
// pre-barrier vmcnt(0)); 2-deep rb ping-pong; se hoisted to registers (static idx).

#define AH(r,c)    Ah[(size_t)(r)*264 + (c)]
#define BHL(s,k,c) Bh[((size_t)((s)*256 + (k)))*40 + (c)]
#define QQ(t,c)    q[(size_t)(t)*260 + (c)]

#define T2I(v, i, v1, i1, v2) { \
  bool lt = (v) < (v1); \
  (v2) = lt ? (v1) : fminf((v2), (v)); \
  (i1) = lt ? (i) : (i1); \
  (v1) = lt ? (v) : (v1); }

#define DECL_T2(M,R) \
  float b1_##M##R = 3.4e38f, b2_##M##R = 3.4e38f; int bi_##M##R = 0x7fffffff;

#define FOLDK(KT,M,R) { \
  float v; \
  v = fmaf(a##M##0[R], NEGI, seh[(KT)*4+0]); T2I(v, (KT)*256 + wcfr +  0, b1_##M##R, bi_##M##R, b2_##M##R); \
  v = fmaf(a##M##1[R], NEGI, seh[(KT)*4+1]); T2I(v, (KT)*256 + wcfr + 16, b1_##M##R, bi_##M##R, b2_##M##R); \
  v = fmaf(a##M##2[R], NEGI, seh[(KT)*4+2]); T2I(v, (KT)*256 + wcfr + 32, b1_##M##R, bi_##M##R, b2_##M##R); \
  v = fmaf(a##M##3[R], NEGI, seh[(KT)*4+3]); T2I(v, (KT)*256 + wcfr + 48, b1_##M##R, bi_##M##R, b2_##M##R); }

#define BSTEP(KT, CC, S) { \
  *(f16x8_t*)&BHL((CC)&1, codeS, cOff)     = rb##S##0; \
  *(f16x8_t*)&BHL((CC)&1, codeS, cOff + 8) = rb##S##1; \
  __syncthreads(); \
  { \
    const int nn = (KT)*8 + (CC) + 2; \
    if (nn < 32){ \
      const _Float16* p_ = cb16 + ((size_t)((nn>>3)*256) + codeS)*DIMS + (nn&7)*32 + cOff; \
      rb##S##0 = *(const f16x8_t*)(p_); rb##S##1 = *(const f16x8_t*)(p_ + 8); \
    } \
  } \
  { \
    f16x8_t bh0 = *(const f16x8_t*)&BHL((CC)&1, bC0, fq8); \
    f16x8_t bh1 = *(const f16x8_t*)&BHL((CC)&1, bC1, fq8); \
    f16x8_t bh2 = *(const f16x8_t*)&BHL((CC)&1, bC2, fq8); \
    f16x8_t bh3 = *(const f16x8_t*)&BHL((CC)&1, bC3, fq8); \
    f16x8_t ah0 = *(const f16x8_t*)&AH(wr32 + fr, (CC)*32 + fq8); \
    f16x8_t ah1 = *(const f16x8_t*)&AH(wr32 + 16 + fr, (CC)*32 + fq8); \
    a00 = __builtin_amdgcn_mfma_f32_16x16x32_f16(ah0, bh0, a00, 0, 0, 0); \
    a01 = __builtin_amdgcn_mfma_f32_16x16x32_f16(ah0, bh1, a01, 0, 0, 0); \
    a02 = __builtin_amdgcn_mfma_f32_16x16x32_f16(ah0, bh2, a02, 0, 0, 0); \
    a03 = __builtin_amdgcn_mfma_f32_16x16x32_f16(ah0, bh3, a03, 0, 0, 0); \
    a10 = __builtin_amdgcn_mfma_f32_16x16x32_f16(ah1, bh0, a10, 0, 0, 0); \
    a11 = __builtin_amdgcn_mfma_f32_16x16x32_f16(ah1, bh1, a11, 0, 0, 0); \
    a12 = __builtin_amdgcn_mfma_f32_16x16x32_f16(ah1, bh2, a12, 0, 0, 0); \
    a13 = __builtin_amdgcn_mfma_f32_16x16x32_f16(ah1, bh3, a13, 0, 0, 0); \
  } }

#define KTSTEP(KT) { \
  BSTEP(KT,0,A) BSTEP(KT,1,B) BSTEP(KT,2,A) BSTEP(KT,3,B) \
  BSTEP(KT,4,A) BSTEP(KT,5,B) BSTEP(KT,6,A) BSTEP(KT,7,B) \
  FOLDK(KT,0,0) FOLDK(KT,0,1) FOLDK(KT,0,2) FOLDK(KT,0,3) \
  FOLDK(KT,1,0) FOLDK(KT,1,1) FOLDK(KT,1,2) FOLDK(KT,1,3) \
  a00=Z;a01=Z;a02=Z;a03=Z; a10=Z;a11=Z;a12=Z;a13=Z; }

#define MSTEP(MK) { \
  float ov1 = __shfl_xor(v1, MK); int oi1 = __shfl_xor(i1, MK); float ov2 = __shfl_xor(v2, MK); \
  bool tk = ov1 < v1; \
  v2 = tk ? fminf(v1, ov2) : fminf(v2, ov1); \
  i1 = tk ? oi1 : i1; \
  v1 = tk ? ov1 : v1; }

#define MERGE(M,R) { \
  float v1 = b1_##M##R, v2 = b2_##M##R; int i1 = bi_##M##R; \
  MSTEP(1) MSTEP(2) MSTEP(4) MSTEP(8) \
  if (fr == 0) comb[(wr32 + (M)*16 + fq*4 + (R))*4 + wc] = make_float4(v1, __int_as_float(i1), v2, 0.f); }

__global__ __launch_bounds__(512, 1) void vq_scores(
    const float* __restrict__ x, const float* __restrict__ cb,
    const _Float16* __restrict__ cb16, const float* __restrict__ se,
    float* __restrict__ out0, float* __restrict__ out2,
    unsigned* __restrict__ wl, unsigned* __restrict__ cnt, double* __restrict__ accd)
{
  // smem: Ah [64][264] f16 @0 (33792B); Bh [2][256][40] f16 @33792 (40960B);
  // comb @74752 (4096B); codeL @78848; sxa @79104. q [64][260] f32 aliases Ah+Bh.
  __shared__ __align__(16) char smem[79360];
  _Float16* Ah   = (_Float16*)smem;
  _Float16* Bh   = (_Float16*)(smem + 33792);
  float4*   comb = (float4*)(smem + 74752);
  int*      codeL= (int*)(smem + 78848);
  float*    sxa  = (float*)(smem + 79104);
  float*    q    = (float*)smem;

  const int tid  = threadIdx.x;
  const int lane = tid & 63;
  const int wid  = tid >> 6;
  const int wr   = wid >> 2;
  const int wc   = wid & 3;
  const int fr   = lane & 15;
  const int fq   = lane >> 4;
  const int wr32 = wr * 32;
  const int fq8  = fq * 8;
  const int wcfr = wc*64 + fr;
  const int n0   = blockIdx.x * 64;
  const int bb   = n0 >> 12;
  const int t0   = n0 & 4095;
  const float NEGI = -1.0f/256.0f;

  const int codeS = tid >> 1;
  const int cOff  = (tid & 1) << 4;

  // hoisted se (static indices only; all-macro kt unroll)
  float seh[16];
  #pragma unroll
  for (int qq = 0; qq < 16; ++qq)
    seh[qq] = se[(qq>>2)*256 + wcfr + (qq&3)*16];

  // 2-deep B prefetch: set A = even steps, set B = odd steps
  f16x8_t rbA0, rbA1, rbB0, rbB1;
  {
    const _Float16* p_ = cb16 + (size_t)codeS * DIMS + cOff;         // step 0
    rbA0 = *(const f16x8_t*)(p_); rbA1 = *(const f16x8_t*)(p_ + 8);
  }
  {
    const _Float16* p_ = cb16 + (size_t)codeS * DIMS + 32 + cOff;    // step 1
    rbB0 = *(const f16x8_t*)(p_); rbB1 = *(const f16x8_t*)(p_ + 8);
  }

  // ---- stage A once: 64 rows x 256 c, fp16 ----
  {
    const int dup = tid >> 7;
    const int c4  = tid & 7;
    const int tt  = ((tid >> 3) & 15) << 2;
    #pragma unroll
    for (int cc2 = 0; cc2 < 2; ++cc2){
      const int c0 = (dup*2 + cc2) * 32;
      const float* xp = x + ((size_t)(bb*DIMS + c0 + c4*4))*NT + t0 + tt;
      float4 va0 = *(const float4*)(xp);
      float4 va1 = *(const float4*)(xp + NT);
      float4 va2 = *(const float4*)(xp + 2*NT);
      float4 va3 = *(const float4*)(xp + 3*NT);
      #pragma unroll
      for (int j = 0; j < 4; ++j){
        f16x4_t p;
        p.x = (_Float16)((&va0.x)[j]);
        p.y = (_Float16)((&va1.x)[j]);
        p.z = (_Float16)((&va2.x)[j]);
        p.w = (_Float16)((&va3.x)[j]);
        *(f16x4_t*)&AH(tt + j, c0 + c4*4) = p;
      }
    }
  }

  const f32x4_t Z = {0.f, 0.f, 0.f, 0.f};
  f32x4_t a00=Z,a01=Z,a02=Z,a03=Z, a10=Z,a11=Z,a12=Z,a13=Z;
  DECL_T2(0,0) DECL_T2(0,1) DECL_T2(0,2) DECL_T2(0,3)
  DECL_T2(1,0) DECL_T2(1,1) DECL_T2(1,2) DECL_T2(1,3)

  const int bC0 = wc*64 + 0*16 + fr;
  const int bC1 = wc*64 + 1*16 + fr;
  const int bC2 = wc*64 + 2*16 + fr;
  const int bC3 = wc*64 + 3*16 + fr;

  KTSTEP(0) KTSTEP(1) KTSTEP(2) KTSTEP(3)

  // cross-lane (fr) merge into comb
  MERGE(0,0) MERGE(0,1) MERGE(0,2) MERGE(0,3)
  MERGE(1,0) MERGE(1,1) MERGE(1,2) MERGE(1,3)
  __syncthreads();

  // approx row norms from staged fp16 A (fused loss; ~1e-4 accuracy is plenty)
  {
    const int row = tid >> 3, seg = tid & 7;
    float s = 0.f;
    #pragma unroll
    for (int k = 0; k < 4; ++k){
      f16x8_t hv = *(const f16x8_t*)&AH(row, seg*32 + k*8);
      #pragma unroll
      for (int e = 0; e < 8; ++e){
        float f = (float)hv[e];
        s = fmaf(f, f, s);
      }
    }
    s += __shfl_xor(s, 1);
    s += __shfl_xor(s, 2);
    s += __shfl_xor(s, 4);
    if (seg == 0) sxa[row] = s;
  }
  __syncthreads();

  if (tid < 64){
    float4 p = comb[tid*4 + 0];
    float v1 = p.x, v2 = p.z;
    int   i1 = __float_as_int(p.y);
    #pragma unroll
    for (int w = 1; w < 4; ++w){
      p = comb[tid*4 + w];
      bool tk = p.x < v1;
      v2 = tk ? fminf(v1, p.z) : fminf(v2, p.x);
      i1 = tk ? __float_as_int(p.y) : i1;
      v1 = tk ? p.x : v1;
    }
    const int r = n0 + tid;
    codeL[tid] = i1;
    out2[r] = (float)i1;
    bool flg = !(v2 - v1 >= THETA);
    if (flg){
      unsigned pos = atomicAdd(cnt, 1u);
      wl[pos] = (unsigned)r;
    }
    double c = flg ? 0.0 : (double)(sxa[tid] + v1);
    #pragma unroll
    for (int m = 1; m < 64; m <<= 1) c += __shfl_xor(c, m);
    if (tid == 0) atomicAdd(accd, c);
  }
  __syncthreads();

  // ---- stage 64 selected fp32 codebook rows into q (aliases Ah/Bh) ----
  {
    const int r = tid >> 3, seg = tid & 7;
    const float* src = cb + (size_t)codeL[r] * DIMS;
    #pragma unroll
    for (int k = 0; k < 8; ++k){
      float4 v = *(const float4*)(src + k*32 + seg*4);
      *(float4*)&QQ(r, k*32 + seg*4) = v;
    }
  }
  __syncthreads();

  // ---- write out0 tile: channel-major, 64B-line coalesced ----
  {
    #pragma unroll
    for (int jj = 0; jj < 2; ++jj){
      const int c = wid*32 + jj*16 + (lane >> 2);
      float* dst = out0 + ((size_t)(bb*256 + c))*NT + t0;
      #pragma unroll
      for (int ii = 0; ii < 4; ++ii){
        const int tl = ii*16 + (lane & 3)*4;
        float4 v;
        v.x = QQ(tl + 0, c);
        v.y = QQ(tl + 1, c);
        v.z = QQ(tl + 2, c);
        v.w = QQ(tl + 3, c);
        *(float4*)(dst + tl) = v;
      }
    }
  }
}

// ---- kernel 2: exact fp32-numpy-emulated re-scan of flagged rows + out0 patch ----
// 16 rows per group (halves full-codebook restaging vs 8).
__global__ __launch_bounds__(256) void vq_refine(
    const float* __restrict__ x, const float* __restrict__ cb,
    const float* __restrict__ se,
    const unsigned* __restrict__ wl, const unsigned* __restrict__ cnt,
    float* __restrict__ out2, float* __restrict__ out0, double* __restrict__ accd)
{
  __shared__ float eT[8][1024];   // 32 KiB transposed codebook chunk
  __shared__ float xs[DIMS][16];  // 16 KiB
  __shared__ int   rows_s[16];
  __shared__ float sxs[16];
  __shared__ float wv[4][16];
  __shared__ int   wi[4][16];
  __shared__ int   wiF[16];

  const unsigned n = *cnt;
  const unsigned groups = (n + 15u) >> 4;
  const int tid  = threadIdx.x;
  const int lane = tid & 63;
  const int wid  = tid >> 6;

  for (unsigned g = blockIdx.x; g < groups; g += gridDim.x){
    __syncthreads();   // protect shared reuse across groups
    if (tid < 16){
      unsigned e = g*16u + (unsigned)tid;
      rows_s[tid] = (int)wl[e < n ? e : (n - 1u)];
    }
    __syncthreads();
    // stage x rows (scattered gather along c)
    #pragma unroll
    for (int rep = 0; rep < 16; ++rep){
      int id = rep * 256 + tid;
      int c = id >> 4, r = id & 15;
      int row = rows_s[r];
      xs[c][r] = x[((size_t)((row >> 12)*DIMS + c))*NT + (row & 4095)];
    }
    __syncthreads();
    // bit-exact sx per row (numpy pairwise: 8-acc chains + fixed tree); 256 thr = 16x16
    {
      const int r = tid >> 4, hj = tid & 15;
      const int h = hj >> 3, j = hj & 7;
      float v0 = xs[h*128 + j][r];
      float s = __fmul_rn(v0, v0);
      #pragma unroll
      for (int i = 1; i < 16; ++i){
        float v = xs[h*128 + j + 8*i][r];
        s = __fadd_rn(s, __fmul_rn(v, v));
      }
      s = __fadd_rn(s, __shfl_xor(s, 1));
      s = __fadd_rn(s, __shfl_xor(s, 2));
      s = __fadd_rn(s, __shfl_xor(s, 4));
      s = __fadd_rn(s, __shfl_xor(s, 8));
      if (hj == 0) sxs[r] = s;
    }

    float s[16][4];
    #pragma unroll
    for (int r = 0; r < 16; ++r)
      #pragma unroll
      for (int u = 0; u < 4; ++u) s[r][u] = 0.f;

    for (int c0 = 0; c0 < DIMS; c0 += 8){
      __syncthreads();
      #pragma unroll
      for (int rep = 0; rep < 8; ++rep){
        int id2 = rep * 256 + tid;
        int k = id2 >> 1, qq = id2 & 1;
        float4 v = *(const float4*)&cb[(size_t)k * DIMS + c0 + qq * 4];
        eT[qq*4 + 0][k] = v.x; eT[qq*4 + 1][k] = v.y;
        eT[qq*4 + 2][k] = v.z; eT[qq*4 + 3][k] = v.w;
      }
      __syncthreads();
      #pragma unroll
      for (int cc = 0; cc < 8; ++cc){
        float4 ev = *(const float4*)&eT[cc][wid*256 + lane*4];
        #pragma unroll
        for (int r = 0; r < 16; ++r){
          float xv = xs[c0 + cc][r];
          s[r][0] = fmaf(xv, ev.x, s[r][0]);
          s[r][1] = fmaf(xv, ev.y, s[r][1]);
          s[r][2] = fmaf(xv, ev.z, s[r][2]);
          s[r][3] = fmaf(xv, ev.w, s[r][3]);
        }
      }
    }

    float4 sek = *(const float4*)&se[wid*256 + lane*4];
    #pragma unroll
    for (int r = 0; r < 16; ++r){
      const float sxv = sxs[r];
      float bv = 3.4e38f; int bi = 0x7fffffff;
      #pragma unroll
      for (int u = 0; u < 4; ++u){
        float d = __fsub_rn(__fadd_rn(sxv, (&sek.x)[u]),
                            __fadd_rn(s[r][u], s[r][u]));
        int k = wid*256 + lane*4 + u;
        if (d < bv || (d == bv && k < bi)) { bv = d; bi = k; }
      }
      #pragma unroll
      for (int m = 1; m < 64; m <<= 1){
        float ov = __shfl_xor(bv, m);
        int   oi = __shfl_xor(bi, m);
        if (ov < bv || (ov == bv && oi < bi)) { bv = ov; bi = oi; }
      }
      if (lane == 0){ wv[wid][r] = bv; wi[wid][r] = bi; }
    }
    __syncthreads();
    if (tid < 16){
      const int r = tid;
      float bv = wv[0][r]; int bi = wi[0][r];
      #pragma unroll
      for (int w = 1; w < 4; ++w){
        float ov = wv[w][r]; int oi = wi[w][r];
        if (ov < bv || (ov == bv && oi < bi)) { bv = ov; bi = oi; }
      }
      wiF[r] = bi;
      if (g*16u + (unsigned)r < n){
        int row = rows_s[r];
        out2[row] = (float)bi;
        atomicAdd(accd, (double)bv);   // exact loss contribution for flagged row
      }
    }
    __syncthreads();
    // patch out0 for flagged rows
    #pragma unroll
    for (int r = 0; r < 16; ++r){
      if (g*16u + (unsigned)r < n){
        int row  = rows_s[r];
        int code = wiF[r];
        out0[((size_t)((row >> 12)*256 + tid))*NT + (row & 4095)] = cb[(size_t)code*DIMS + tid];
      }
    }
  }
}

__global__ void vq_final(const double* __restrict__ accd, float* __restrict__ out1){
  *out1 = (float)(1.25 * (*accd) * (1.0 / 16777216.0));
}

extern "C" void kernel_launch(void* const* d_in, const int* in_sizes, int n_in,
                              void* d_out, int out_size, void* d_ws, size_t ws_size,
                              hipStream_t stream)
{
  const float* x  = (const float*)d_in[0];
  const float* cb = (const float*)d_in[1];
  float* out  = (float*)d_out;
  float* out0 = out;
  float* out1 = out + (size_t)16777216;   // vq_loss
  float* out2 = out + (size_t)16777217;   // indices as float [65536]

  char* ws = (char*)d_ws;
  double*   accd = (double*)(ws + 0);
  unsigned* cnt  = (unsigned*)(ws + 8);
  float*    se   = (float*)(ws + 64);       // 4 KiB
  unsigned* wl   = (unsigned*)(ws + 4160);  // 256 KiB worklist
  _Float16* cb16 = (_Float16*)(ws + 266304);// 512 KiB fp16 codebook (x512)

  hipMemsetAsync(d_ws, 0, 16, stream);      // zero loss accumulator + worklist count
  vq_prep  <<<dim3(1024), dim3(64),  0, stream>>>(cb, se, cb16);
  vq_scores<<<dim3(1024), dim3(512), 0, stream>>>(x, cb, cb16, se, out0, out2, wl, cnt, accd);
  vq_refine<<<dim3(512),  dim3(256), 0, stream>>>(x, cb, se, wl, cnt, out2, out0, accd);
  vq_final <<<dim3(1),    dim3(1),   0, stream>>>(accd, out1);
}

// Round 13
// 184.324 us; speedup vs baseline: 1.0918x; 1.0918x over previous
//
#include <hip/hip_runtime.h>
#include <stdint.h>

#define DIMS 256
#define NT 4096
#define NROWS 65536
#define THETA 1.5e-4f

typedef float    f32x4_t __attribute__((ext_vector_type(4)));
typedef _Float16 f16x8_t __attribute__((ext_vector_type(8)));
typedef _Float16 f16x4_t __attribute__((ext_vector_type(4)));

// ---- kernel 0: fused se (bit-exact numpy pairwise) + cb16 = fp16(cb*512) ----
__global__ __launch_bounds__(64) void vq_prep(const float* __restrict__ cb,
                                              float* __restrict__ se,
                                              _Float16* __restrict__ cb16){
  __shared__ float sq[256];
  const int k = blockIdx.x;
  const int tid = threadIdx.x;
  float4 v = *(const float4*)(cb + (size_t)k*256 + tid*4);
  f16x4_t p;
  p.x = (_Float16)(v.x * 512.f);
  p.y = (_Float16)(v.y * 512.f);
  p.z = (_Float16)(v.z * 512.f);
  p.w = (_Float16)(v.w * 512.f);
  *(f16x4_t*)(cb16 + (size_t)k*256 + tid*4) = p;
  sq[tid*4+0] = __fmul_rn(v.x, v.x);
  sq[tid*4+1] = __fmul_rn(v.y, v.y);
  sq[tid*4+2] = __fmul_rn(v.z, v.z);
  sq[tid*4+3] = __fmul_rn(v.w, v.w);
  __syncthreads();
  if (tid < 16){
    const int h = tid >> 3, j = tid & 7;
    float r = sq[h*128 + j];
    #pragma unroll
    for (int i = 1; i < 16; ++i) r = __fadd_rn(r, sq[h*128 + j + 8*i]);
    r = __fadd_rn(r, __shfl_xor(r, 1));
    r = __fadd_rn(r, __shfl_xor(r, 2));
    r = __fadd_rn(r, __shfl_xor(r, 4));
    r = __fadd_rn(r, __shfl_xor(r, 8));
    if (tid == 0) se[k] = r;
  }
}

// ================= kernel 1: scores + fused loss + fused output write =================
// 64 rows/block x 1024 codes; 8 waves: wr = row-half (M=2), wc = 64-code stripe.
// RAW s_barrier K-loop (no vmcnt drain): ds_write -> lgkmcnt(0) -> s_barrier -> prefetch
// issue -> ds_read+MFMA. 2-deep rb ping-pong survives barriers (counted vmcnt only).

#define AH(r,c)    Ah[(size_t)(r)*264 + (c)]
#define BHL(s,k,c) Bh[((size_t)((s)*256 + (k)))*40 + (c)]
#define QQ(t,c)    q[(size_t)(t)*260 + (c)]

#define T2I(v, i, v1, i1, v2) { \
  bool lt = (v) < (v1); \
  (v2) = lt ? (v1) : fminf((v2), (v)); \
  (i1) = lt ? (i) : (i1); \
  (v1) = lt ? (v) : (v1); }

#define DECL_T2(M,R) \
  float b1_##M##R = 3.4e38f, b2_##M##R = 3.4e38f; int bi_##M##R = 0x7fffffff;

#define FOLD(M,R) { \
  float v; \
  v = fmaf(a##M##0[R], NEGI, ec0); T2I(v, kb +  0, b1_##M##R, bi_##M##R, b2_##M##R); \
  v = fmaf(a##M##1[R], NEGI, ec1); T2I(v, kb + 16, b1_##M##R, bi_##M##R, b2_##M##R); \
  v = fmaf(a##M##2[R], NEGI, ec2); T2I(v, kb + 32, b1_##M##R, bi_##M##R, b2_##M##R); \
  v = fmaf(a##M##3[R], NEGI, ec3); T2I(v, kb + 48, b1_##M##R, bi_##M##R, b2_##M##R); }

#define BSTEP(CC, S) { \
  *(f16x8_t*)&BHL((CC)&1, codeS, cOff)     = rb##S##0; \
  *(f16x8_t*)&BHL((CC)&1, codeS, cOff + 8) = rb##S##1; \
  asm volatile("s_waitcnt lgkmcnt(0)" ::: "memory"); \
  __builtin_amdgcn_s_barrier(); \
  asm volatile("" ::: "memory"); \
  { \
    const int nn = ktb + (CC) + 2; \
    if (nn < 32){ \
      const _Float16* p_ = cb16 + ((size_t)((nn>>3)*256) + codeS)*DIMS + (nn&7)*32 + cOff; \
      rb##S##0 = *(const f16x8_t*)(p_); rb##S##1 = *(const f16x8_t*)(p_ + 8); \
    } \
  } \
  { \
    f16x8_t bh0 = *(const f16x8_t*)&BHL((CC)&1, bC0, fq8); \
    f16x8_t bh1 = *(const f16x8_t*)&BHL((CC)&1, bC1, fq8); \
    f16x8_t bh2 = *(const f16x8_t*)&BHL((CC)&1, bC2, fq8); \
    f16x8_t bh3 = *(const f16x8_t*)&BHL((CC)&1, bC3, fq8); \
    f16x8_t ah0 = *(const f16x8_t*)&AH(wr32 + fr, (CC)*32 + fq8); \
    f16x8_t ah1 = *(const f16x8_t*)&AH(wr32 + 16 + fr, (CC)*32 + fq8); \
    a00 = __builtin_amdgcn_mfma_f32_16x16x32_f16(ah0, bh0, a00, 0, 0, 0); \
    a01 = __builtin_amdgcn_mfma_f32_16x16x32_f16(ah0, bh1, a01, 0, 0, 0); \
    a02 = __builtin_amdgcn_mfma_f32_16x16x32_f16(ah0, bh2, a02, 0, 0, 0); \
    a03 = __builtin_amdgcn_mfma_f32_16x16x32_f16(ah0, bh3, a03, 0, 0, 0); \
    a10 = __builtin_amdgcn_mfma_f32_16x16x32_f16(ah1, bh0, a10, 0, 0, 0); \
    a11 = __builtin_amdgcn_mfma_f32_16x16x32_f16(ah1, bh1, a11, 0, 0, 0); \
    a12 = __builtin_amdgcn_mfma_f32_16x16x32_f16(ah1, bh2, a12, 0, 0, 0); \
    a13 = __builtin_amdgcn_mfma_f32_16x16x32_f16(ah1, bh3, a13, 0, 0, 0); \
  } }

#define MSTEP(MK) { \
  float ov1 = __shfl_xor(v1, MK); int oi1 = __shfl_xor(i1, MK); float ov2 = __shfl_xor(v2, MK); \
  bool tk = ov1 < v1; \
  v2 = tk ? fminf(v1, ov2) : fminf(v2, ov1); \
  i1 = tk ? oi1 : i1; \
  v1 = tk ? ov1 : v1; }

#define MERGE(M,R) { \
  float v1 = b1_##M##R, v2 = b2_##M##R; int i1 = bi_##M##R; \
  MSTEP(1) MSTEP(2) MSTEP(4) MSTEP(8) \
  if (fr == 0) comb[(wr32 + (M)*16 + fq*4 + (R))*4 + wc] = make_float4(v1, __int_as_float(i1), v2, 0.f); }

__global__ __launch_bounds__(512, 1) void vq_scores(
    const float* __restrict__ x, const float* __restrict__ cb,
    const _Float16* __restrict__ cb16, const float* __restrict__ se,
    float* __restrict__ out0, float* __restrict__ out2,
    unsigned* __restrict__ wl, unsigned* __restrict__ cnt, double* __restrict__ accd)
{
  // smem: Ah [64][264] f16 @0 (33792B); Bh [2][256][40] f16 @33792 (40960B);
  // comb @74752 (4096B); codeL @78848; sxa @79104. q [64][260] f32 aliases Ah+Bh.
  __shared__ __align__(16) char smem[79360];
  _Float16* Ah   = (_Float16*)smem;
  _Float16* Bh   = (_Float16*)(smem + 33792);
  float4*   comb = (float4*)(smem + 74752);
  int*      codeL= (int*)(smem + 78848);
  float*    sxa  = (float*)(smem + 79104);
  float*    q    = (float*)smem;

  const int tid  = threadIdx.x;
  const int lane = tid & 63;
  const int wid  = tid >> 6;
  const int wr   = wid >> 2;
  const int wc   = wid & 3;
  const int fr   = lane & 15;
  const int fq   = lane >> 4;
  const int wr32 = wr * 32;
  const int fq8  = fq * 8;
  const int wcfr = wc*64 + fr;
  const int n0   = blockIdx.x * 64;
  const int bb   = n0 >> 12;
  const int t0   = n0 & 4095;
  const float NEGI = -1.0f/256.0f;

  const int codeS = tid >> 1;
  const int cOff  = (tid & 1) << 4;

  // 2-deep B prefetch: set A = even steps, set B = odd steps
  f16x8_t rbA0, rbA1, rbB0, rbB1;
  {
    const _Float16* p_ = cb16 + (size_t)codeS * DIMS + cOff;         // step 0
    rbA0 = *(const f16x8_t*)(p_); rbA1 = *(const f16x8_t*)(p_ + 8);
  }
  {
    const _Float16* p_ = cb16 + (size_t)codeS * DIMS + 32 + cOff;    // step 1
    rbB0 = *(const f16x8_t*)(p_); rbB1 = *(const f16x8_t*)(p_ + 8);
  }

  // ---- stage A once: 64 rows x 256 c, fp16 ----
  {
    const int dup = tid >> 7;
    const int c4  = tid & 7;
    const int tt  = ((tid >> 3) & 15) << 2;
    #pragma unroll
    for (int cc2 = 0; cc2 < 2; ++cc2){
      const int c0 = (dup*2 + cc2) * 32;
      const float* xp = x + ((size_t)(bb*DIMS + c0 + c4*4))*NT + t0 + tt;
      float4 va0 = *(const float4*)(xp);
      float4 va1 = *(const float4*)(xp + NT);
      float4 va2 = *(const float4*)(xp + 2*NT);
      float4 va3 = *(const float4*)(xp + 3*NT);
      #pragma unroll
      for (int j = 0; j < 4; ++j){
        f16x4_t p;
        p.x = (_Float16)((&va0.x)[j]);
        p.y = (_Float16)((&va1.x)[j]);
        p.z = (_Float16)((&va2.x)[j]);
        p.w = (_Float16)((&va3.x)[j]);
        *(f16x4_t*)&AH(tt + j, c0 + c4*4) = p;
      }
    }
  }

  const f32x4_t Z = {0.f, 0.f, 0.f, 0.f};
  f32x4_t a00=Z,a01=Z,a02=Z,a03=Z, a10=Z,a11=Z,a12=Z,a13=Z;
  DECL_T2(0,0) DECL_T2(0,1) DECL_T2(0,2) DECL_T2(0,3)
  DECL_T2(1,0) DECL_T2(1,1) DECL_T2(1,2) DECL_T2(1,3)

  const int bC0 = wc*64 + 0*16 + fr;
  const int bC1 = wc*64 + 1*16 + fr;
  const int bC2 = wc*64 + 2*16 + fr;
  const int bC3 = wc*64 + 3*16 + fr;

  for (int kt = 0; kt < 4; ++kt){
    const int ktb = kt * 8;
    BSTEP(0,A) BSTEP(1,B) BSTEP(2,A) BSTEP(3,B)
    BSTEP(4,A) BSTEP(5,B) BSTEP(6,A) BSTEP(7,B)

    const int kb = kt*256 + wcfr;
    const float ec0 = se[kb], ec1 = se[kb+16], ec2 = se[kb+32], ec3 = se[kb+48];
    FOLD(0,0) FOLD(0,1) FOLD(0,2) FOLD(0,3)
    FOLD(1,0) FOLD(1,1) FOLD(1,2) FOLD(1,3)
    a00=Z;a01=Z;a02=Z;a03=Z; a10=Z;a11=Z;a12=Z;a13=Z;
  }

  // cross-lane (fr) merge into comb
  MERGE(0,0) MERGE(0,1) MERGE(0,2) MERGE(0,3)
  MERGE(1,0) MERGE(1,1) MERGE(1,2) MERGE(1,3)
  __syncthreads();

  // approx row norms from staged fp16 A (fused loss; ~1e-4 accuracy is plenty)
  {
    const int row = tid >> 3, seg = tid & 7;
    float s = 0.f;
    #pragma unroll
    for (int k = 0; k < 4; ++k){
      f16x8_t hv = *(const f16x8_t*)&AH(row, seg*32 + k*8);
      #pragma unroll
      for (int e = 0; e < 8; ++e){
        float f = (float)hv[e];
        s = fmaf(f, f, s);
      }
    }
    s += __shfl_xor(s, 1);
    s += __shfl_xor(s, 2);
    s += __shfl_xor(s, 4);
    if (seg == 0) sxa[row] = s;
  }
  __syncthreads();

  if (tid < 64){
    float4 p = comb[tid*4 + 0];
    float v1 = p.x, v2 = p.z;
    int   i1 = __float_as_int(p.y);
    #pragma unroll
    for (int w = 1; w < 4; ++w){
      p = comb[tid*4 + w];
      bool tk = p.x < v1;
      v2 = tk ? fminf(v1, p.z) : fminf(v2, p.x);
      i1 = tk ? __float_as_int(p.y) : i1;
      v1 = tk ? p.x : v1;
    }
    const int r = n0 + tid;
    codeL[tid] = i1;
    out2[r] = (float)i1;
    bool flg = !(v2 - v1 >= THETA);
    if (flg){
      unsigned pos = atomicAdd(cnt, 1u);
      wl[pos] = (unsigned)r;
    }
    double c = flg ? 0.0 : (double)(sxa[tid] + v1);
    #pragma unroll
    for (int m = 1; m < 64; m <<= 1) c += __shfl_xor(c, m);
    if (tid == 0) atomicAdd(accd, c);
  }
  __syncthreads();

  // ---- stage 64 selected fp32 codebook rows into q (aliases Ah/Bh) ----
  {
    const int r = tid >> 3, seg = tid & 7;
    const float* src = cb + (size_t)codeL[r] * DIMS;
    #pragma unroll
    for (int k = 0; k < 8; ++k){
      float4 v = *(const float4*)(src + k*32 + seg*4);
      *(float4*)&QQ(r, k*32 + seg*4) = v;
    }
  }
  __syncthreads();

  // ---- write out0 tile: channel-major, 64B-line coalesced ----
  {
    #pragma unroll
    for (int jj = 0; jj < 2; ++jj){
      const int c = wid*32 + jj*16 + (lane >> 2);
      float* dst = out0 + ((size_t)(bb*256 + c))*NT + t0;
      #pragma unroll
      for (int ii = 0; ii < 4; ++ii){
        const int tl = ii*16 + (lane & 3)*4;
        float4 v;
        v.x = QQ(tl + 0, c);
        v.y = QQ(tl + 1, c);
        v.z = QQ(tl + 2, c);
        v.w = QQ(tl + 3, c);
        *(float4*)(dst + tl) = v;
      }
    }
  }
}

// ---- kernel 2: exact fp32-numpy-emulated re-scan of flagged rows + out0 patch ----
// 16 rows per group (halves full-codebook restaging vs 8).
__global__ __launch_bounds__(256) void vq_refine(
    const float* __restrict__ x, const float* __restrict__ cb,
    const float* __restrict__ se,
    const unsigned* __restrict__ wl, const unsigned* __restrict__ cnt,
    float* __restrict__ out2, float* __restrict__ out0, double* __restrict__ accd)
{
  __shared__ float eT[8][1024];   // 32 KiB transposed codebook chunk
  __shared__ float xs[DIMS][16];  // 16 KiB
  __shared__ int   rows_s[16];
  __shared__ float sxs[16];
  __shared__ float wv[4][16];
  __shared__ int   wi[4][16];
  __shared__ int   wiF[16];

  const unsigned n = *cnt;
  const unsigned groups = (n + 15u) >> 4;
  const int tid  = threadIdx.x;
  const int lane = tid & 63;
  const int wid  = tid >> 6;

  for (unsigned g = blockIdx.x; g < groups; g += gridDim.x){
    __syncthreads();   // protect shared reuse across groups
    if (tid < 16){
      unsigned e = g*16u + (unsigned)tid;
      rows_s[tid] = (int)wl[e < n ? e : (n - 1u)];
    }
    __syncthreads();
    // stage x rows (scattered gather along c)
    #pragma unroll
    for (int rep = 0; rep < 16; ++rep){
      int id = rep * 256 + tid;
      int c = id >> 4, r = id & 15;
      int row = rows_s[r];
      xs[c][r] = x[((size_t)((row >> 12)*DIMS + c))*NT + (row & 4095)];
    }
    __syncthreads();
    // bit-exact sx per row (numpy pairwise: 8-acc chains + fixed tree); 256 thr = 16x16
    {
      const int r = tid >> 4, hj = tid & 15;
      const int h = hj >> 3, j = hj & 7;
      float v0 = xs[h*128 + j][r];
      float s = __fmul_rn(v0, v0);
      #pragma unroll
      for (int i = 1; i < 16; ++i){
        float v = xs[h*128 + j + 8*i][r];
        s = __fadd_rn(s, __fmul_rn(v, v));
      }
      s = __fadd_rn(s, __shfl_xor(s, 1));
      s = __fadd_rn(s, __shfl_xor(s, 2));
      s = __fadd_rn(s, __shfl_xor(s, 4));
      s = __fadd_rn(s, __shfl_xor(s, 8));
      if (hj == 0) sxs[r] = s;
    }

    float s[16][4];
    #pragma unroll
    for (int r = 0; r < 16; ++r)
      #pragma unroll
      for (int u = 0; u < 4; ++u) s[r][u] = 0.f;

    for (int c0 = 0; c0 < DIMS; c0 += 8){
      __syncthreads();
      #pragma unroll
      for (int rep = 0; rep < 8; ++rep){
        int id2 = rep * 256 + tid;
        int k = id2 >> 1, qq = id2 & 1;
        float4 v = *(const float4*)&cb[(size_t)k * DIMS + c0 + qq * 4];
        eT[qq*4 + 0][k] = v.x; eT[qq*4 + 1][k] = v.y;
        eT[qq*4 + 2][k] = v.z; eT[qq*4 + 3][k] = v.w;
      }
      __syncthreads();
      #pragma unroll
      for (int cc = 0; cc < 8; ++cc){
        float4 ev = *(const float4*)&eT[cc][wid*256 + lane*4];
        #pragma unroll
        for (int r = 0; r < 16; ++r){
          float xv = xs[c0 + cc][r];
          s[r][0] = fmaf(xv, ev.x, s[r][0]);
          s[r][1] = fmaf(xv, ev.y, s[r][1]);
          s[r][2] = fmaf(xv, ev.z, s[r][2]);
          s[r][3] = fmaf(xv, ev.w, s[r][3]);
        }
      }
    }

    float4 sek = *(const float4*)&se[wid*256 + lane*4];
    #pragma unroll
    for (int r = 0; r < 16; ++r){
      const float sxv = sxs[r];
      float bv = 3.4e38f; int bi = 0x7fffffff;
      #pragma unroll
      for (int u = 0; u < 4; ++u){
        float d = __fsub_rn(__fadd_rn(sxv, (&sek.x)[u]),
                            __fadd_rn(s[r][u], s[r][u]));
        int k = wid*256 + lane*4 + u;
        if (d < bv || (d == bv && k < bi)) { bv = d; bi = k; }
      }
      #pragma unroll
      for (int m = 1; m < 64; m <<= 1){
        float ov = __shfl_xor(bv, m);
        int   oi = __shfl_xor(bi, m);
        if (ov < bv || (ov == bv && oi < bi)) { bv = ov; bi = oi; }
      }
      if (lane == 0){ wv[wid][r] = bv; wi[wid][r] = bi; }
    }
    __syncthreads();
    if (tid < 16){
      const int r = tid;
      float bv = wv[0][r]; int bi = wi[0][r];
      #pragma unroll
      for (int w = 1; w < 4; ++w){
        float ov = wv[w][r]; int oi = wi[w][r];
        if (ov < bv || (ov == bv && oi < bi)) { bv = ov; bi = oi; }
      }
      wiF[r] = bi;
      if (g*16u + (unsigned)r < n){
        int row = rows_s[r];
        out2[row] = (float)bi;
        atomicAdd(accd, (double)bv);   // exact loss contribution for flagged row
      }
    }
    __syncthreads();
    // patch out0 for flagged rows
    #pragma unroll
    for (int r = 0; r < 16; ++r){
      if (g*16u + (unsigned)r < n){
        int row  = rows_s[r];
        int code = wiF[r];
        out0[((size_t)((row >> 12)*256 + tid))*NT + (row & 4095)] = cb[(size_t)code*DIMS + tid];
      }
    }
  }
}

__global__ void vq_final(const double* __restrict__ accd, float* __restrict__ out1){
  *out1 = (float)(1.25 * (*accd) * (1.0 / 16777216.0));
}

extern "C" void kernel_launch(void* const* d_in, const int* in_sizes, int n_in,
                              void* d_out, int out_size, void* d_ws, size_t ws_size,
                              hipStream_t stream)
{
  const float* x  = (const float*)d_in[0];
  const float* cb = (const float*)d_in[1];
  float* out  = (float*)d_out;
  float* out0 = out;
  float* out1 = out + (size_t)16777216;   // vq_loss
  float* out2 = out + (size_t)16777217;   // indices as float [65536]

  char* ws = (char*)d_ws;
  double*   accd = (double*)(ws + 0);
  unsigned* cnt  = (unsigned*)(ws + 8);
  float*    se   = (float*)(ws + 64);       // 4 KiB
  unsigned* wl   = (unsigned*)(ws + 4160);  // 256 KiB worklist
  _Float16* cb16 = (_Float16*)(ws + 266304);// 512 KiB fp16 codebook (x512)

  hipMemsetAsync(d_ws, 0, 16, stream);      // zero loss accumulator + worklist count
  vq_prep  <<<dim3(1024), dim3(64),  0, stream>>>(cb, se, cb16);
  vq_scores<<<dim3(1024), dim3(512), 0, stream>>>(x, cb, cb16, se, out0, out2, wl, cnt, accd);
  vq_refine<<<dim3(512),  dim3(256), 0, stream>>>(x, cb, se, wl, cnt, out2, out0, accd);
  vq_final <<<dim3(1),    dim3(1),   0, stream>>>(accd, out1);
}

// Round 14
// 174.230 us; speedup vs baseline: 1.1551x; 1.0579x over previous
//
#include <hip/hip_runtime.h>
#include <stdint.h>

#define DIMS 256
#define NT 4096
#define NROWS 65536
#define THETA 1.5e-4f

typedef float    f32x4_t __attribute__((ext_vector_type(4)));
typedef _Float16 f16x8_t __attribute__((ext_vector_type(8)));
typedef _Float16 f16x4_t __attribute__((ext_vector_type(4)));

// ---- kernel 0: fused se (bit-exact numpy pairwise) + cb16 = fp16(cb*512) ----
__global__ __launch_bounds__(64) void vq_prep(const float* __restrict__ cb,
                                              float* __restrict__ se,
                                              _Float16* __restrict__ cb16){
  __shared__ float sq[256];
  const int k = blockIdx.x;
  const int tid = threadIdx.x;
  float4 v = *(const float4*)(cb + (size_t)k*256 + tid*4);
  f16x4_t p;
  p.x = (_Float16)(v.x * 512.f);
  p.y = (_Float16)(v.y * 512.f);
  p.z = (_Float16)(v.z * 512.f);
  p.w = (_Float16)(v.w * 512.f);
  *(f16x4_t*)(cb16 + (size_t)k*256 + tid*4) = p;
  sq[tid*4+0] = __fmul_rn(v.x, v.x);
  sq[tid*4+1] = __fmul_rn(v.y, v.y);
  sq[tid*4+2] = __fmul_rn(v.z, v.z);
  sq[tid*4+3] = __fmul_rn(v.w, v.w);
  __syncthreads();
  if (tid < 16){
    const int h = tid >> 3, j = tid & 7;
    float r = sq[h*128 + j];
    #pragma unroll
    for (int i = 1; i < 16; ++i) r = __fadd_rn(r, sq[h*128 + j + 8*i]);
    r = __fadd_rn(r, __shfl_xor(r, 1));
    r = __fadd_rn(r, __shfl_xor(r, 2));
    r = __fadd_rn(r, __shfl_xor(r, 4));
    r = __fadd_rn(r, __shfl_xor(r, 8));
    if (tid == 0) se[k] = r;
  }
}

// ================= kernel 1: scores + fused loss + fused output write =================
// 64 rows/block x 1024 codes; 8 waves: wr = row-half (M=2), wc = 64-code stripe.
// NT loads on x (zero reuse -> keep cb16 L2-resident); NT stores on out0 (never read).

#define AH(r,c)    Ah[(size_t)(r)*264 + (c)]
#define BHL(s,k,c) Bh[((size_t)((s)*256 + (k)))*40 + (c)]
#define QQ(t,c)    q[(size_t)(t)*260 + (c)]

#define T2I(v, i, v1, i1, v2) { \
  bool lt = (v) < (v1); \
  (v2) = lt ? (v1) : fminf((v2), (v)); \
  (i1) = lt ? (i) : (i1); \
  (v1) = lt ? (v) : (v1); }

#define DECL_T2(M,R) \
  float b1_##M##R = 3.4e38f, b2_##M##R = 3.4e38f; int bi_##M##R = 0x7fffffff;

#define FOLD(M,R) { \
  float v; \
  v = fmaf(a##M##0[R], NEGI, ec0); T2I(v, kb +  0, b1_##M##R, bi_##M##R, b2_##M##R); \
  v = fmaf(a##M##1[R], NEGI, ec1); T2I(v, kb + 16, b1_##M##R, bi_##M##R, b2_##M##R); \
  v = fmaf(a##M##2[R], NEGI, ec2); T2I(v, kb + 32, b1_##M##R, bi_##M##R, b2_##M##R); \
  v = fmaf(a##M##3[R], NEGI, ec3); T2I(v, kb + 48, b1_##M##R, bi_##M##R, b2_##M##R); }

#define BSTEP(CC, S) { \
  *(f16x8_t*)&BHL((CC)&1, codeS, cOff)     = rb##S##0; \
  *(f16x8_t*)&BHL((CC)&1, codeS, cOff + 8) = rb##S##1; \
  asm volatile("s_waitcnt lgkmcnt(0)" ::: "memory"); \
  __builtin_amdgcn_s_barrier(); \
  asm volatile("" ::: "memory"); \
  { \
    const int nn = ktb + (CC) + 2; \
    if (nn < 32){ \
      const _Float16* p_ = cb16 + ((size_t)((nn>>3)*256) + codeS)*DIMS + (nn&7)*32 + cOff; \
      rb##S##0 = *(const f16x8_t*)(p_); rb##S##1 = *(const f16x8_t*)(p_ + 8); \
    } \
  } \
  { \
    f16x8_t bh0 = *(const f16x8_t*)&BHL((CC)&1, bC0, fq8); \
    f16x8_t bh1 = *(const f16x8_t*)&BHL((CC)&1, bC1, fq8); \
    f16x8_t bh2 = *(const f16x8_t*)&BHL((CC)&1, bC2, fq8); \
    f16x8_t bh3 = *(const f16x8_t*)&BHL((CC)&1, bC3, fq8); \
    f16x8_t ah0 = *(const f16x8_t*)&AH(wr32 + fr, (CC)*32 + fq8); \
    f16x8_t ah1 = *(const f16x8_t*)&AH(wr32 + 16 + fr, (CC)*32 + fq8); \
    a00 = __builtin_amdgcn_mfma_f32_16x16x32_f16(ah0, bh0, a00, 0, 0, 0); \
    a01 = __builtin_amdgcn_mfma_f32_16x16x32_f16(ah0, bh1, a01, 0, 0, 0); \
    a02 = __builtin_amdgcn_mfma_f32_16x16x32_f16(ah0, bh2, a02, 0, 0, 0); \
    a03 = __builtin_amdgcn_mfma_f32_16x16x32_f16(ah0, bh3, a03, 0, 0, 0); \
    a10 = __builtin_amdgcn_mfma_f32_16x16x32_f16(ah1, bh0, a10, 0, 0, 0); \
    a11 = __builtin_amdgcn_mfma_f32_16x16x32_f16(ah1, bh1, a11, 0, 0, 0); \
    a12 = __builtin_amdgcn_mfma_f32_16x16x32_f16(ah1, bh2, a12, 0, 0, 0); \
    a13 = __builtin_amdgcn_mfma_f32_16x16x32_f16(ah1, bh3, a13, 0, 0, 0); \
  } }

#define MSTEP(MK) { \
  float ov1 = __shfl_xor(v1, MK); int oi1 = __shfl_xor(i1, MK); float ov2 = __shfl_xor(v2, MK); \
  bool tk = ov1 < v1; \
  v2 = tk ? fminf(v1, ov2) : fminf(v2, ov1); \
  i1 = tk ? oi1 : i1; \
  v1 = tk ? ov1 : v1; }

#define MERGE(M,R) { \
  float v1 = b1_##M##R, v2 = b2_##M##R; int i1 = bi_##M##R; \
  MSTEP(1) MSTEP(2) MSTEP(4) MSTEP(8) \
  if (fr == 0) comb[(wr32 + (M)*16 + fq*4 + (R))*4 + wc] = make_float4(v1, __int_as_float(i1), v2, 0.f); }

__global__ __launch_bounds__(512, 1) void vq_scores(
    const float* __restrict__ x, const float* __restrict__ cb,
    const _Float16* __restrict__ cb16, const float* __restrict__ se,
    float* __restrict__ out0, float* __restrict__ out2,
    unsigned* __restrict__ wl, unsigned* __restrict__ cnt, double* __restrict__ accd)
{
  // smem: Ah [64][264] f16 @0 (33792B); Bh [2][256][40] f16 @33792 (40960B);
  // comb @74752 (4096B); codeL @78848; sxa @79104. q [64][260] f32 aliases Ah+Bh.
  __shared__ __align__(16) char smem[79360];
  _Float16* Ah   = (_Float16*)smem;
  _Float16* Bh   = (_Float16*)(smem + 33792);
  float4*   comb = (float4*)(smem + 74752);
  int*      codeL= (int*)(smem + 78848);
  float*    sxa  = (float*)(smem + 79104);
  float*    q    = (float*)smem;

  const int tid  = threadIdx.x;
  const int lane = tid & 63;
  const int wid  = tid >> 6;
  const int wr   = wid >> 2;
  const int wc   = wid & 3;
  const int fr   = lane & 15;
  const int fq   = lane >> 4;
  const int wr32 = wr * 32;
  const int fq8  = fq * 8;
  const int wcfr = wc*64 + fr;
  const int n0   = blockIdx.x * 64;
  const int bb   = n0 >> 12;
  const int t0   = n0 & 4095;
  const float NEGI = -1.0f/256.0f;

  const int codeS = tid >> 1;
  const int cOff  = (tid & 1) << 4;

  // 2-deep B prefetch: set A = even steps, set B = odd steps
  f16x8_t rbA0, rbA1, rbB0, rbB1;
  {
    const _Float16* p_ = cb16 + (size_t)codeS * DIMS + cOff;         // step 0
    rbA0 = *(const f16x8_t*)(p_); rbA1 = *(const f16x8_t*)(p_ + 8);
  }
  {
    const _Float16* p_ = cb16 + (size_t)codeS * DIMS + 32 + cOff;    // step 1
    rbB0 = *(const f16x8_t*)(p_); rbB1 = *(const f16x8_t*)(p_ + 8);
  }

  // ---- stage A once: 64 rows x 256 c, fp16; NT loads (x has zero reuse) ----
  {
    const int dup = tid >> 7;
    const int c4  = tid & 7;
    const int tt  = ((tid >> 3) & 15) << 2;
    #pragma unroll
    for (int cc2 = 0; cc2 < 2; ++cc2){
      const int c0 = (dup*2 + cc2) * 32;
      const float* xp = x + ((size_t)(bb*DIMS + c0 + c4*4))*NT + t0 + tt;
      f32x4_t va0 = __builtin_nontemporal_load((const f32x4_t*)(xp));
      f32x4_t va1 = __builtin_nontemporal_load((const f32x4_t*)(xp + NT));
      f32x4_t va2 = __builtin_nontemporal_load((const f32x4_t*)(xp + 2*NT));
      f32x4_t va3 = __builtin_nontemporal_load((const f32x4_t*)(xp + 3*NT));
      #pragma unroll
      for (int j = 0; j < 4; ++j){
        f16x4_t p;
        p.x = (_Float16)(va0[j]);
        p.y = (_Float16)(va1[j]);
        p.z = (_Float16)(va2[j]);
        p.w = (_Float16)(va3[j]);
        *(f16x4_t*)&AH(tt + j, c0 + c4*4) = p;
      }
    }
  }

  const f32x4_t Z = {0.f, 0.f, 0.f, 0.f};
  f32x4_t a00=Z,a01=Z,a02=Z,a03=Z, a10=Z,a11=Z,a12=Z,a13=Z;
  DECL_T2(0,0) DECL_T2(0,1) DECL_T2(0,2) DECL_T2(0,3)
  DECL_T2(1,0) DECL_T2(1,1) DECL_T2(1,2) DECL_T2(1,3)

  const int bC0 = wc*64 + 0*16 + fr;
  const int bC1 = wc*64 + 1*16 + fr;
  const int bC2 = wc*64 + 2*16 + fr;
  const int bC3 = wc*64 + 3*16 + fr;

  for (int kt = 0; kt < 4; ++kt){
    const int ktb = kt * 8;
    BSTEP(0,A) BSTEP(1,B) BSTEP(2,A) BSTEP(3,B)
    BSTEP(4,A) BSTEP(5,B) BSTEP(6,A) BSTEP(7,B)

    const int kb = kt*256 + wcfr;
    const float ec0 = se[kb], ec1 = se[kb+16], ec2 = se[kb+32], ec3 = se[kb+48];
    FOLD(0,0) FOLD(0,1) FOLD(0,2) FOLD(0,3)
    FOLD(1,0) FOLD(1,1) FOLD(1,2) FOLD(1,3)
    a00=Z;a01=Z;a02=Z;a03=Z; a10=Z;a11=Z;a12=Z;a13=Z;
  }

  // cross-lane (fr) merge into comb
  MERGE(0,0) MERGE(0,1) MERGE(0,2) MERGE(0,3)
  MERGE(1,0) MERGE(1,1) MERGE(1,2) MERGE(1,3)
  __syncthreads();

  // approx row norms from staged fp16 A (fused loss; ~1e-4 accuracy is plenty)
  {
    const int row = tid >> 3, seg = tid & 7;
    float s = 0.f;
    #pragma unroll
    for (int k = 0; k < 4; ++k){
      f16x8_t hv = *(const f16x8_t*)&AH(row, seg*32 + k*8);
      #pragma unroll
      for (int e = 0; e < 8; ++e){
        float f = (float)hv[e];
        s = fmaf(f, f, s);
      }
    }
    s += __shfl_xor(s, 1);
    s += __shfl_xor(s, 2);
    s += __shfl_xor(s, 4);
    if (seg == 0) sxa[row] = s;
  }
  __syncthreads();

  if (tid < 64){
    float4 p = comb[tid*4 + 0];
    float v1 = p.x, v2 = p.z;
    int   i1 = __float_as_int(p.y);
    #pragma unroll
    for (int w = 1; w < 4; ++w){
      p = comb[tid*4 + w];
      bool tk = p.x < v1;
      v2 = tk ? fminf(v1, p.z) : fminf(v2, p.x);
      i1 = tk ? __float_as_int(p.y) : i1;
      v1 = tk ? p.x : v1;
    }
    const int r = n0 + tid;
    codeL[tid] = i1;
    out2[r] = (float)i1;
    bool flg = !(v2 - v1 >= THETA);
    if (flg){
      unsigned pos = atomicAdd(cnt, 1u);
      wl[pos] = (unsigned)r;
    }
    double c = flg ? 0.0 : (double)(sxa[tid] + v1);
    #pragma unroll
    for (int m = 1; m < 64; m <<= 1) c += __shfl_xor(c, m);
    if (tid == 0) atomicAdd(accd, c);
  }
  __syncthreads();

  // ---- stage 64 selected fp32 codebook rows into q (aliases Ah/Bh) ----
  {
    const int r = tid >> 3, seg = tid & 7;
    const float* src = cb + (size_t)codeL[r] * DIMS;
    #pragma unroll
    for (int k = 0; k < 8; ++k){
      float4 v = *(const float4*)(src + k*32 + seg*4);
      *(float4*)&QQ(r, k*32 + seg*4) = v;
    }
  }
  __syncthreads();

  // ---- write out0 tile: channel-major, 64B-line coalesced; NT stores ----
  {
    #pragma unroll
    for (int jj = 0; jj < 2; ++jj){
      const int c = wid*32 + jj*16 + (lane >> 2);
      float* dst = out0 + ((size_t)(bb*256 + c))*NT + t0;
      #pragma unroll
      for (int ii = 0; ii < 4; ++ii){
        const int tl = ii*16 + (lane & 3)*4;
        f32x4_t v;
        v[0] = QQ(tl + 0, c);
        v[1] = QQ(tl + 1, c);
        v[2] = QQ(tl + 2, c);
        v[3] = QQ(tl + 3, c);
        __builtin_nontemporal_store(v, (f32x4_t*)(dst + tl));
      }
    }
  }
}

// ---- kernel 2: exact fp32-numpy-emulated re-scan of flagged rows + out0 patch ----
// 8 rows per group (more parallel groups -> shorter critical path than 16).
__global__ __launch_bounds__(256) void vq_refine(
    const float* __restrict__ x, const float* __restrict__ cb,
    const float* __restrict__ se,
    const unsigned* __restrict__ wl, const unsigned* __restrict__ cnt,
    float* __restrict__ out2, float* __restrict__ out0, double* __restrict__ accd)
{
  __shared__ float eT[8][1024];   // 32 KiB transposed codebook chunk
  __shared__ float xs[DIMS][8];   // 8 KiB
  __shared__ int   rows_s[8];
  __shared__ float sxs[8];
  __shared__ float wv[4][8];
  __shared__ int   wi[4][8];
  __shared__ int   wiF[8];

  const unsigned n = *cnt;
  const unsigned groups = (n + 7u) >> 3;
  const int tid  = threadIdx.x;
  const int lane = tid & 63;
  const int wid  = tid >> 6;

  for (unsigned g = blockIdx.x; g < groups; g += gridDim.x){
    __syncthreads();   // protect shared reuse across groups
    if (tid < 8){
      unsigned e = g*8u + (unsigned)tid;
      rows_s[tid] = (int)wl[e < n ? e : (n - 1u)];
    }
    __syncthreads();
    // stage x rows (scattered gather along c)
    #pragma unroll
    for (int rep = 0; rep < 8; ++rep){
      int id = rep * 256 + tid;
      int c = id >> 3, r = id & 7;
      int row = rows_s[r];
      xs[c][r] = x[((size_t)((row >> 12)*DIMS + c))*NT + (row & 4095)];
    }
    __syncthreads();
    // bit-exact sx per row (numpy pairwise: 8-acc chains + fixed tree); 128 thr = 8x16
    if (tid < 128){
      const int r = tid >> 4, hj = tid & 15;
      const int h = hj >> 3, j = hj & 7;
      float v0 = xs[h*128 + j][r];
      float s = __fmul_rn(v0, v0);
      #pragma unroll
      for (int i = 1; i < 16; ++i){
        float v = xs[h*128 + j + 8*i][r];
        s = __fadd_rn(s, __fmul_rn(v, v));
      }
      s = __fadd_rn(s, __shfl_xor(s, 1));
      s = __fadd_rn(s, __shfl_xor(s, 2));
      s = __fadd_rn(s, __shfl_xor(s, 4));
      s = __fadd_rn(s, __shfl_xor(s, 8));
      if (hj == 0) sxs[r] = s;
    }

    float s[8][4];
    #pragma unroll
    for (int r = 0; r < 8; ++r)
      #pragma unroll
      for (int u = 0; u < 4; ++u) s[r][u] = 0.f;

    for (int c0 = 0; c0 < DIMS; c0 += 8){
      __syncthreads();
      #pragma unroll
      for (int rep = 0; rep < 8; ++rep){
        int id2 = rep * 256 + tid;
        int k = id2 >> 1, qq = id2 & 1;
        float4 v = *(const float4*)&cb[(size_t)k * DIMS + c0 + qq * 4];
        eT[qq*4 + 0][k] = v.x; eT[qq*4 + 1][k] = v.y;
        eT[qq*4 + 2][k] = v.z; eT[qq*4 + 3][k] = v.w;
      }
      __syncthreads();
      #pragma unroll
      for (int cc = 0; cc < 8; ++cc){
        float4 ev = *(const float4*)&eT[cc][wid*256 + lane*4];
        #pragma unroll
        for (int r = 0; r < 8; ++r){
          float xv = xs[c0 + cc][r];
          s[r][0] = fmaf(xv, ev.x, s[r][0]);
          s[r][1] = fmaf(xv, ev.y, s[r][1]);
          s[r][2] = fmaf(xv, ev.z, s[r][2]);
          s[r][3] = fmaf(xv, ev.w, s[r][3]);
        }
      }
    }

    float4 sek = *(const float4*)&se[wid*256 + lane*4];
    #pragma unroll
    for (int r = 0; r < 8; ++r){
      const float sxv = sxs[r];
      float bv = 3.4e38f; int bi = 0x7fffffff;
      #pragma unroll
      for (int u = 0; u < 4; ++u){
        float d = __fsub_rn(__fadd_rn(sxv, (&sek.x)[u]),
                            __fadd_rn(s[r][u], s[r][u]));
        int k = wid*256 + lane*4 + u;
        if (d < bv || (d == bv && k < bi)) { bv = d; bi = k; }
      }
      #pragma unroll
      for (int m = 1; m < 64; m <<= 1){
        float ov = __shfl_xor(bv, m);
        int   oi = __shfl_xor(bi, m);
        if (ov < bv || (ov == bv && oi < bi)) { bv = ov; bi = oi; }
      }
      if (lane == 0){ wv[wid][r] = bv; wi[wid][r] = bi; }
    }
    __syncthreads();
    if (tid < 8){
      const int r = tid;
      float bv = wv[0][r]; int bi = wi[0][r];
      #pragma unroll
      for (int w = 1; w < 4; ++w){
        float ov = wv[w][r]; int oi = wi[w][r];
        if (ov < bv || (ov == bv && oi < bi)) { bv = ov; bi = oi; }
      }
      wiF[r] = bi;
      if (g*8u + (unsigned)r < n){
        int row = rows_s[r];
        out2[row] = (float)bi;
        atomicAdd(accd, (double)bv);   // exact loss contribution for flagged row
      }
    }
    __syncthreads();
    // patch out0 for flagged rows
    #pragma unroll
    for (int r = 0; r < 8; ++r){
      if (g*8u + (unsigned)r < n){
        int row  = rows_s[r];
        int code = wiF[r];
        out0[((size_t)((row >> 12)*256 + tid))*NT + (row & 4095)] = cb[(size_t)code*DIMS + tid];
      }
    }
  }
}

__global__ void vq_final(const double* __restrict__ accd, float* __restrict__ out1){
  *out1 = (float)(1.25 * (*accd) * (1.0 / 16777216.0));
}

extern "C" void kernel_launch(void* const* d_in, const int* in_sizes, int n_in,
                              void* d_out, int out_size, void* d_ws, size_t ws_size,
                              hipStream_t stream)
{
  const float* x  = (const float*)d_in[0];
  const float* cb = (const float*)d_in[1];
  float* out  = (float*)d_out;
  float* out0 = out;
  float* out1 = out + (size_t)16777216;   // vq_loss
  float* out2 = out + (size_t)16777217;   // indices as float [65536]

  char* ws = (char*)d_ws;
  double*   accd = (double*)(ws + 0);
  unsigned* cnt  = (unsigned*)(ws + 8);
  float*    se   = (float*)(ws + 64);       // 4 KiB
  unsigned* wl   = (unsigned*)(ws + 4160);  // 256 KiB worklist
  _Float16* cb16 = (_Float16*)(ws + 266304);// 512 KiB fp16 codebook (x512)

  hipMemsetAsync(d_ws, 0, 16, stream);      // zero loss accumulator + worklist count
  vq_prep  <<<dim3(1024), dim3(64),  0, stream>>>(cb, se, cb16);
  vq_scores<<<dim3(1024), dim3(512), 0, stream>>>(x, cb, cb16, se, out0, out2, wl, cnt, accd);
  vq_refine<<<dim3(512),  dim3(256), 0, stream>>>(x, cb, se, wl, cnt, out2, out0, accd);
  vq_final <<<dim3(1),    dim3(1),   0, stream>>>(accd, out1);
}

// Round 15
// 159.554 us; speedup vs baseline: 1.2613x; 1.0920x over previous
//
#include <hip/hip_runtime.h>
#include <stdint.h>

#define DIMS 256
#define NT 4096
#define NROWS 65536
#define THETA 1.5e-4f

typedef float    f32x4_t __attribute__((ext_vector_type(4)));
typedef _Float16 f16x8_t __attribute__((ext_vector_type(8)));
typedef _Float16 f16x4_t __attribute__((ext_vector_type(4)));

#define GLDS16(gsrc, ldst) \
  __builtin_amdgcn_global_load_lds((const __attribute__((address_space(1))) void*)(gsrc), \
      (__attribute__((address_space(3))) void*)(ldst), 16, 0, 0)

// ---- kernel 0: fused se (bit-exact numpy pairwise) + cb16 = fp16(cb*512) ----
__global__ __launch_bounds__(64) void vq_prep(const float* __restrict__ cb,
                                              float* __restrict__ se,
                                              _Float16* __restrict__ cb16){
  __shared__ float sq[256];
  const int k = blockIdx.x;
  const int tid = threadIdx.x;
  float4 v = *(const float4*)(cb + (size_t)k*256 + tid*4);
  f16x4_t p;
  p.x = (_Float16)(v.x * 512.f);
  p.y = (_Float16)(v.y * 512.f);
  p.z = (_Float16)(v.z * 512.f);
  p.w = (_Float16)(v.w * 512.f);
  *(f16x4_t*)(cb16 + (size_t)k*256 + tid*4) = p;
  sq[tid*4+0] = __fmul_rn(v.x, v.x);
  sq[tid*4+1] = __fmul_rn(v.y, v.y);
  sq[tid*4+2] = __fmul_rn(v.z, v.z);
  sq[tid*4+3] = __fmul_rn(v.w, v.w);
  __syncthreads();
  if (tid < 16){
    const int h = tid >> 3, j = tid & 7;
    float r = sq[h*128 + j];
    #pragma unroll
    for (int i = 1; i < 16; ++i) r = __fadd_rn(r, sq[h*128 + j + 8*i]);
    r = __fadd_rn(r, __shfl_xor(r, 1));
    r = __fadd_rn(r, __shfl_xor(r, 2));
    r = __fadd_rn(r, __shfl_xor(r, 4));
    r = __fadd_rn(r, __shfl_xor(r, 8));
    if (tid == 0) se[k] = r;
  }
}

// ================= kernel 1: scores, glds B-staging, swizzled LDS =================
// 64 rows/block x 1024 codes; 8 waves: wr = row-half (M=2), wc = 64-code stripe.
// B staged by global_load_lds (16B/lane, per-lane swizzled SOURCE, linear dest).
// Layout: content (code c, quarter q) at byte c*64 + ((q ^ ((c>>1)&3))<<4)  -> uniform banks.
// Phase: vmcnt(0) -> s_barrier -> issue glds(p+1) -> ds_read + MFMA(setprio).

#define AH(r,c)    Ah[(size_t)(r)*264 + (c)]
#define QQ(t,c)    q[(size_t)(t)*260 + (c)]

#define T2I(v, i, v1, i1, v2) { \
  bool lt = (v) < (v1); \
  (v2) = lt ? (v1) : fminf((v2), (v)); \
  (i1) = lt ? (i) : (i1); \
  (v1) = lt ? (v) : (v1); }

#define DECL_T2(M,R) \
  float b1_##M##R = 3.4e38f, b2_##M##R = 3.4e38f; int bi_##M##R = 0x7fffffff;

#define FOLD(M,R) { \
  float v; \
  v = fmaf(a##M##0[R], NEGI, ec0); T2I(v, kb +  0, b1_##M##R, bi_##M##R, b2_##M##R); \
  v = fmaf(a##M##1[R], NEGI, ec1); T2I(v, kb + 16, b1_##M##R, bi_##M##R, b2_##M##R); \
  v = fmaf(a##M##2[R], NEGI, ec2); T2I(v, kb + 32, b1_##M##R, bi_##M##R, b2_##M##R); \
  v = fmaf(a##M##3[R], NEGI, ec3); T2I(v, kb + 48, b1_##M##R, bi_##M##R, b2_##M##R); }

#define MSTEP(MK) { \
  float ov1 = __shfl_xor(v1, MK); int oi1 = __shfl_xor(i1, MK); float ov2 = __shfl_xor(v2, MK); \
  bool tk = ov1 < v1; \
  v2 = tk ? fminf(v1, ov2) : fminf(v2, ov1); \
  i1 = tk ? oi1 : i1; \
  v1 = tk ? ov1 : v1; }

#define MERGE(M,R) { \
  float v1 = b1_##M##R, v2 = b2_##M##R; int i1 = bi_##M##R; \
  MSTEP(1) MSTEP(2) MSTEP(4) MSTEP(8) \
  if (fr == 0) comb[(wr32 + (M)*16 + fq*4 + (R))*4 + wc] = make_float4(v1, __int_as_float(i1), v2, 0.f); }

__global__ __launch_bounds__(512, 1) void vq_scores(
    const float* __restrict__ x, const float* __restrict__ cb,
    const _Float16* __restrict__ cb16, const float* __restrict__ se,
    float* __restrict__ out0, float* __restrict__ out2,
    unsigned* __restrict__ wl, unsigned* __restrict__ cnt, double* __restrict__ accd)
{
  // smem: Ah [64][264] f16 @0 (33792B); Bh linear 2x16384 @33792; comb @66560 (4096B);
  // codeL @70656; sxa @70912. Total 71168. q [64][260] f32 (66560B) aliases Ah+Bh.
  __shared__ __align__(16) char smem[71168];
  _Float16* Ah   = (_Float16*)smem;
  char*     BhRaw= smem + 33792;
  float4*   comb = (float4*)(smem + 66560);
  int*      codeL= (int*)(smem + 70656);
  float*    sxa  = (float*)(smem + 70912);
  float*    q    = (float*)smem;

  const int tid  = threadIdx.x;
  const int lane = tid & 63;
  const int wid  = tid >> 6;
  const int wr   = wid >> 2;
  const int wc   = wid & 3;
  const int fr   = lane & 15;
  const int fq   = lane >> 4;
  const int wr32 = wr * 32;
  const int fq8  = fq * 8;
  const int wcfr = wc*64 + fr;
  const int n0   = blockIdx.x * 64;
  const int bb   = n0 >> 12;
  const int t0   = n0 & 4095;
  const float NEGI = -1.0f/256.0f;

  // per-lane glds source offsets (inverse swizzle on global src; LDS dest linear)
  const int cA = wid*32 + (lane >> 2);
  const int cB = cA + 16;
  const int qA = (lane & 3) ^ ((cA >> 1) & 3);
  const int qB = (lane & 3) ^ ((cB >> 1) & 3);
  const char* cbB = (const char*)cb16;
  const size_t srcA = (size_t)cA*512 + qA*16;
  const size_t srcB = (size_t)cB*512 + qB*16;
  char* dstA = BhRaw + wid*2048;          // HW adds lane*16
  char* dstB = dstA + 1024;

  // per-lane swizzled read offsets for the 4 B fragments
  int bOff[4];
  #pragma unroll
  for (int cf = 0; cf < 4; ++cf){
    const int cd = wc*64 + cf*16 + fr;
    bOff[cf] = cd*64 + ((fq ^ ((cd >> 1) & 3)) << 4);
  }

  // prologue: stage phase-0 B chunk into buf0 (covered by HBM A-staging below)
  GLDS16(cbB + srcA, dstA);
  GLDS16(cbB + srcB, dstB);

  // ---- stage A once: 64 rows x 256 c, fp16; NT loads (x has zero reuse) ----
  {
    const int dup = tid >> 7;
    const int c4  = tid & 7;
    const int tt  = ((tid >> 3) & 15) << 2;
    #pragma unroll
    for (int cc2 = 0; cc2 < 2; ++cc2){
      const int c0 = (dup*2 + cc2) * 32;
      const float* xp = x + ((size_t)(bb*DIMS + c0 + c4*4))*NT + t0 + tt;
      f32x4_t va0 = __builtin_nontemporal_load((const f32x4_t*)(xp));
      f32x4_t va1 = __builtin_nontemporal_load((const f32x4_t*)(xp + NT));
      f32x4_t va2 = __builtin_nontemporal_load((const f32x4_t*)(xp + 2*NT));
      f32x4_t va3 = __builtin_nontemporal_load((const f32x4_t*)(xp + 3*NT));
      #pragma unroll
      for (int j = 0; j < 4; ++j){
        f16x4_t p;
        p.x = (_Float16)(va0[j]);
        p.y = (_Float16)(va1[j]);
        p.z = (_Float16)(va2[j]);
        p.w = (_Float16)(va3[j]);
        *(f16x4_t*)&AH(tt + j, c0 + c4*4) = p;
      }
    }
  }
  comb[(tid >> 2)*4 + (tid & 3)] = make_float4(3.4e38f, __int_as_float(0x7fffffff), 3.4e38f, 0.f);

  const f32x4_t Z = {0.f, 0.f, 0.f, 0.f};
  f32x4_t a00=Z,a01=Z,a02=Z,a03=Z, a10=Z,a11=Z,a12=Z,a13=Z;
  DECL_T2(0,0) DECL_T2(0,1) DECL_T2(0,2) DECL_T2(0,3)
  DECL_T2(1,0) DECL_T2(1,1) DECL_T2(1,2) DECL_T2(1,3)

  __syncthreads();   // full drain: A-tile visible, prologue glds landed

  for (int p = 0; p < 32; ++p){
    if (p){
      asm volatile("s_waitcnt vmcnt(0)" ::: "memory");   // glds(p) landed (everyone's, + barrier)
      __builtin_amdgcn_s_barrier();
      asm volatile("" ::: "memory");
    }
    const int nn = p + 1;
    if (nn < 32){
      const char* g = cbB + (size_t)(nn >> 3)*131072 + (size_t)(nn & 7)*64;
      char* d = (nn & 1) ? (dstA + 16384) : dstA;
      GLDS16(g + srcA, d);
      GLDS16(g + srcB, d + 1024);
    }
    {
      const char* bbuf = BhRaw + ((p & 1) << 14);
      f16x8_t bh0 = *(const f16x8_t*)(bbuf + bOff[0]);
      f16x8_t bh1 = *(const f16x8_t*)(bbuf + bOff[1]);
      f16x8_t bh2 = *(const f16x8_t*)(bbuf + bOff[2]);
      f16x8_t bh3 = *(const f16x8_t*)(bbuf + bOff[3]);
      const int cc = p & 7;
      f16x8_t ah0 = *(const f16x8_t*)&AH(wr32 + fr, cc*32 + fq8);
      f16x8_t ah1 = *(const f16x8_t*)&AH(wr32 + 16 + fr, cc*32 + fq8);
      __builtin_amdgcn_s_setprio(1);
      a00 = __builtin_amdgcn_mfma_f32_16x16x32_f16(ah0, bh0, a00, 0, 0, 0);
      a01 = __builtin_amdgcn_mfma_f32_16x16x32_f16(ah0, bh1, a01, 0, 0, 0);
      a02 = __builtin_amdgcn_mfma_f32_16x16x32_f16(ah0, bh2, a02, 0, 0, 0);
      a03 = __builtin_amdgcn_mfma_f32_16x16x32_f16(ah0, bh3, a03, 0, 0, 0);
      a10 = __builtin_amdgcn_mfma_f32_16x16x32_f16(ah1, bh0, a10, 0, 0, 0);
      a11 = __builtin_amdgcn_mfma_f32_16x16x32_f16(ah1, bh1, a11, 0, 0, 0);
      a12 = __builtin_amdgcn_mfma_f32_16x16x32_f16(ah1, bh2, a12, 0, 0, 0);
      a13 = __builtin_amdgcn_mfma_f32_16x16x32_f16(ah1, bh3, a13, 0, 0, 0);
      __builtin_amdgcn_s_setprio(0);
    }
    if ((p & 7) == 7){
      const int kb = (p >> 3)*256 + wcfr;
      const float ec0 = se[kb], ec1 = se[kb+16], ec2 = se[kb+32], ec3 = se[kb+48];
      FOLD(0,0) FOLD(0,1) FOLD(0,2) FOLD(0,3)
      FOLD(1,0) FOLD(1,1) FOLD(1,2) FOLD(1,3)
      a00=Z;a01=Z;a02=Z;a03=Z; a10=Z;a11=Z;a12=Z;a13=Z;
    }
  }

  // cross-lane (fr) merge into comb
  MERGE(0,0) MERGE(0,1) MERGE(0,2) MERGE(0,3)
  MERGE(1,0) MERGE(1,1) MERGE(1,2) MERGE(1,3)
  __syncthreads();

  // approx row norms from staged fp16 A (fused loss; ~1e-4 accuracy is plenty)
  {
    const int row = tid >> 3, seg = tid & 7;
    float s = 0.f;
    #pragma unroll
    for (int k = 0; k < 4; ++k){
      f16x8_t hv = *(const f16x8_t*)&AH(row, seg*32 + k*8);
      #pragma unroll
      for (int e = 0; e < 8; ++e){
        float f = (float)hv[e];
        s = fmaf(f, f, s);
      }
    }
    s += __shfl_xor(s, 1);
    s += __shfl_xor(s, 2);
    s += __shfl_xor(s, 4);
    if (seg == 0) sxa[row] = s;
  }
  __syncthreads();

  if (tid < 64){
    float4 pv = comb[tid*4 + 0];
    float v1 = pv.x, v2 = pv.z;
    int   i1 = __float_as_int(pv.y);
    #pragma unroll
    for (int w = 1; w < 4; ++w){
      pv = comb[tid*4 + w];
      bool tk = pv.x < v1;
      v2 = tk ? fminf(v1, pv.z) : fminf(v2, pv.x);
      i1 = tk ? __float_as_int(pv.y) : i1;
      v1 = tk ? pv.x : v1;
    }
    const int r = n0 + tid;
    codeL[tid] = i1;
    out2[r] = (float)i1;
    bool flg = !(v2 - v1 >= THETA);
    if (flg){
      unsigned pos = atomicAdd(cnt, 1u);
      wl[pos] = (unsigned)r;
    }
    double c = flg ? 0.0 : (double)(sxa[tid] + v1);
    #pragma unroll
    for (int m = 1; m < 64; m <<= 1) c += __shfl_xor(c, m);
    if (tid == 0) atomicAdd(accd, c);
  }
  __syncthreads();

  // ---- stage 64 selected fp32 codebook rows into q (aliases Ah/Bh) ----
  {
    const int r = tid >> 3, seg = tid & 7;
    const float* src = cb + (size_t)codeL[r] * DIMS;
    #pragma unroll
    for (int k = 0; k < 8; ++k){
      float4 v = *(const float4*)(src + k*32 + seg*4);
      *(float4*)&QQ(r, k*32 + seg*4) = v;
    }
  }
  __syncthreads();

  // ---- write out0 tile: channel-major, 64B-line coalesced; NT stores ----
  {
    #pragma unroll
    for (int jj = 0; jj < 2; ++jj){
      const int c = wid*32 + jj*16 + (lane >> 2);
      float* dst = out0 + ((size_t)(bb*256 + c))*NT + t0;
      #pragma unroll
      for (int ii = 0; ii < 4; ++ii){
        const int tl = ii*16 + (lane & 3)*4;
        f32x4_t v;
        v[0] = QQ(tl + 0, c);
        v[1] = QQ(tl + 1, c);
        v[2] = QQ(tl + 2, c);
        v[3] = QQ(tl + 3, c);
        __builtin_nontemporal_store(v, (f32x4_t*)(dst + tl));
      }
    }
  }
}

// ---- kernel 2: exact fp32-numpy-emulated re-scan of flagged rows + out0 patch ----
__global__ __launch_bounds__(256) void vq_refine(
    const float* __restrict__ x, const float* __restrict__ cb,
    const float* __restrict__ se,
    const unsigned* __restrict__ wl, const unsigned* __restrict__ cnt,
    float* __restrict__ out2, float* __restrict__ out0, double* __restrict__ accd)
{
  __shared__ float eT[8][1024];   // 32 KiB transposed codebook chunk
  __shared__ float xs[DIMS][8];   // 8 KiB
  __shared__ int   rows_s[8];
  __shared__ float sxs[8];
  __shared__ float wv[4][8];
  __shared__ int   wi[4][8];
  __shared__ int   wiF[8];

  const unsigned n = *cnt;
  const unsigned groups = (n + 7u) >> 3;
  const int tid  = threadIdx.x;
  const int lane = tid & 63;
  const int wid  = tid >> 6;

  for (unsigned g = blockIdx.x; g < groups; g += gridDim.x){
    __syncthreads();
    if (tid < 8){
      unsigned e = g*8u + (unsigned)tid;
      rows_s[tid] = (int)wl[e < n ? e : (n - 1u)];
    }
    __syncthreads();
    #pragma unroll
    for (int rep = 0; rep < 8; ++rep){
      int id = rep * 256 + tid;
      int c = id >> 3, r = id & 7;
      int row = rows_s[r];
      xs[c][r] = x[((size_t)((row >> 12)*DIMS + c))*NT + (row & 4095)];
    }
    __syncthreads();
    if (tid < 128){
      const int r = tid >> 4, hj = tid & 15;
      const int h = hj >> 3, j = hj & 7;
      float v0 = xs[h*128 + j][r];
      float s = __fmul_rn(v0, v0);
      #pragma unroll
      for (int i = 1; i < 16; ++i){
        float v = xs[h*128 + j + 8*i][r];
        s = __fadd_rn(s, __fmul_rn(v, v));
      }
      s = __fadd_rn(s, __shfl_xor(s, 1));
      s = __fadd_rn(s, __shfl_xor(s, 2));
      s = __fadd_rn(s, __shfl_xor(s, 4));
      s = __fadd_rn(s, __shfl_xor(s, 8));
      if (hj == 0) sxs[r] = s;
    }

    float s[8][4];
    #pragma unroll
    for (int r = 0; r < 8; ++r)
      #pragma unroll
      for (int u = 0; u < 4; ++u) s[r][u] = 0.f;

    for (int c0 = 0; c0 < DIMS; c0 += 8){
      __syncthreads();
      #pragma unroll
      for (int rep = 0; rep < 8; ++rep){
        int id2 = rep * 256 + tid;
        int k = id2 >> 1, qq = id2 & 1;
        float4 v = *(const float4*)&cb[(size_t)k * DIMS + c0 + qq * 4];
        eT[qq*4 + 0][k] = v.x; eT[qq*4 + 1][k] = v.y;
        eT[qq*4 + 2][k] = v.z; eT[qq*4 + 3][k] = v.w;
      }
      __syncthreads();
      #pragma unroll
      for (int cc = 0; cc < 8; ++cc){
        float4 ev = *(const float4*)&eT[cc][wid*256 + lane*4];
        #pragma unroll
        for (int r = 0; r < 8; ++r){
          float xv = xs[c0 + cc][r];
          s[r][0] = fmaf(xv, ev.x, s[r][0]);
          s[r][1] = fmaf(xv, ev.y, s[r][1]);
          s[r][2] = fmaf(xv, ev.z, s[r][2]);
          s[r][3] = fmaf(xv, ev.w, s[r][3]);
        }
      }
    }

    float4 sek = *(const float4*)&se[wid*256 + lane*4];
    #pragma unroll
    for (int r = 0; r < 8; ++r){
      const float sxv = sxs[r];
      float bv = 3.4e38f; int bi = 0x7fffffff;
      #pragma unroll
      for (int u = 0; u < 4; ++u){
        float d = __fsub_rn(__fadd_rn(sxv, (&sek.x)[u]),
                            __fadd_rn(s[r][u], s[r][u]));
        int k = wid*256 + lane*4 + u;
        if (d < bv || (d == bv && k < bi)) { bv = d; bi = k; }
      }
      #pragma unroll
      for (int m = 1; m < 64; m <<= 1){
        float ov = __shfl_xor(bv, m);
        int   oi = __shfl_xor(bi, m);
        if (ov < bv || (ov == bv && oi < bi)) { bv = ov; bi = oi; }
      }
      if (lane == 0){ wv[wid][r] = bv; wi[wid][r] = bi; }
    }
    __syncthreads();
    if (tid < 8){
      const int r = tid;
      float bv = wv[0][r]; int bi = wi[0][r];
      #pragma unroll
      for (int w = 1; w < 4; ++w){
        float ov = wv[w][r]; int oi = wi[w][r];
        if (ov < bv || (ov == bv && oi < bi)) { bv = ov; bi = oi; }
      }
      wiF[r] = bi;
      if (g*8u + (unsigned)r < n){
        int row = rows_s[r];
        out2[row] = (float)bi;
        atomicAdd(accd, (double)bv);
      }
    }
    __syncthreads();
    #pragma unroll
    for (int r = 0; r < 8; ++r){
      if (g*8u + (unsigned)r < n){
        int row  = rows_s[r];
        int code = wiF[r];
        out0[((size_t)((row >> 12)*256 + tid))*NT + (row & 4095)] = cb[(size_t)code*DIMS + tid];
      }
    }
  }
}

__global__ void vq_final(const double* __restrict__ accd, float* __restrict__ out1){
  *out1 = (float)(1.25 * (*accd) * (1.0 / 16777216.0));
}

extern "C" void kernel_launch(void* const* d_in, const int* in_sizes, int n_in,
                              void* d_out, int out_size, void* d_ws, size_t ws_size,
                              hipStream_t stream)
{
  const float* x  = (const float*)d_in[0];
  const float* cb = (const float*)d_in[1];
  float* out  = (float*)d_out;
  float* out0 = out;
  float* out1 = out + (size_t)16777216;   // vq_loss
  float* out2 = out + (size_t)16777217;   // indices as float [65536]

  char* ws = (char*)d_ws;
  double*   accd = (double*)(ws + 0);
  unsigned* cnt  = (unsigned*)(ws + 8);
  float*    se   = (float*)(ws + 64);       // 4 KiB
  unsigned* wl   = (unsigned*)(ws + 4160);  // 256 KiB worklist
  _Float16* cb16 = (_Float16*)(ws + 266304);// 512 KiB fp16 codebook (x512)

  hipMemsetAsync(d_ws, 0, 16, stream);      // zero loss accumulator + worklist count
  vq_prep  <<<dim3(1024), dim3(64),  0, stream>>>(cb, se, cb16);
  vq_scores<<<dim3(1024), dim3(512), 0, stream>>>(x, cb, cb16, se, out0, out2, wl, cnt, accd);
  vq_refine<<<dim3(512),  dim3(256), 0, stream>>>(x, cb, se, wl, cnt, out2, out0, accd);
  vq_final <<<dim3(1),    dim3(1),   0, stream>>>(accd, out1);
}